// Round 9
// baseline (421.836 us; speedup 1.0000x reference)
//
#include <hip/hip_runtime.h>
#include <hip/hip_bf16.h>
#include <stdint.h>

// Rs_GCN fused pipeline, MI355X (gfx950).
// Algebra: y = (theta phi^T /N) g  ==  theta @ (phi^T g)/N  (no softmax -> associativity).
// W_y = theta @ P, P = (phi^T g) W_w^T / N.  W_b dropped (exact under BatchNorm).
// R9: memory-traffic round (8-phase k_proj rewrite CANCELLED: at K=1024 the verified
// 8-phase stack is 848 TF (m248) vs our current ~858 TF 2-barrier -- no gain at shallow K).
// (1) k_out residual reads vbf (bf16, 64 MiB) instead of v (fp32, 128 MiB): -64 MiB.
//     Wy and Mp un-aliased from vbf (workspace >=512 MiB, we use <200).
// (2) k_wy + k_proj theta-path epilogues: LDS repack -> coalesced short8 stores
//     (was 64/16 scalar 2B stores per thread at 512-elem row stride).
// Floors: fill ~78 (harness), cast ~31, proj ~60 (2-barrier ceiling @ K=1024),
// affin ~13 (mem roofline), out ~42 after this round.

using bf16 = __hip_bfloat16;
typedef __attribute__((ext_vector_type(8))) short short8;
typedef __attribute__((ext_vector_type(4))) float f32x4;
typedef __attribute__((ext_vector_type(4))) short short4v;

#define DEVI static __device__ __forceinline__

DEVI float bf2f(unsigned short u) {
  union { unsigned int i; float f; } x; x.i = ((unsigned int)u) << 16; return x.f;
}
DEVI unsigned short f2bf(float f) {
  __hip_bfloat16 h = __float2bfloat16(f);
  return *reinterpret_cast<unsigned short*>(&h);
}

DEVI void gld16(const void* g, void* l) {
  __builtin_amdgcn_global_load_lds((__attribute__((address_space(1))) void*)g,
                                   (__attribute__((address_space(3))) void*)l,
                                   16, 0, 0);
}

DEVI short8 cvt8(float4 a, float4 b) {
  short8 o;
  o[0] = (short)f2bf(a.x); o[1] = (short)f2bf(a.y);
  o[2] = (short)f2bf(a.z); o[3] = (short)f2bf(a.w);
  o[4] = (short)f2bf(b.x); o[5] = (short)f2bf(b.y);
  o[6] = (short)f2bf(b.z); o[7] = (short)f2bf(b.w);
  return o;
}

// ---- 128x128 tile, BK=32, 256 thr (4 waves 2x2). Swizzled LDS (conflict-free ds_read,
// measured R3); used by short-K kernels k_affin/k_pt. ----
DEVI void mfma_loop(const bf16* A, int ldA, const bf16* B, int ldB,
                    int kiters, bf16* lds_a, bf16* lds_b, f32x4 acc[4][4])
{
  const int tid = threadIdx.x;
  const int lane = tid & 63;
  const int w = tid >> 6;
  const int wr = w >> 1, wc = w & 1;
  const int srow = w * 32 + (lane >> 2);
  const int scol = (((lane & 3) ^ ((srow >> 1) & 3))) * 8;   // source-side swizzle
  const bf16* ga0 = A + (size_t)srow * ldA + scol;
  const bf16* ga1 = A + (size_t)(srow + 16) * ldA + scol;
  const bf16* gb0 = B + (size_t)srow * ldB + scol;
  const bf16* gb1 = B + (size_t)(srow + 16) * ldB + scol;
  bf16* la0 = lds_a + w * 1024 + lane * 8;
  bf16* la1 = la0 + 512;
  bf16* lb0 = lds_b + w * 1024 + lane * 8;
  bf16* lb1 = lb0 + 512;
  const int frow = lane & 15;
  const int fk = (((lane >> 4) ^ ((frow >> 1) & 3))) * 8;    // read-side swizzle (same XOR)
  const bf16* ra = lds_a + (wr * 64 + frow) * 32 + fk;
  const bf16* rb = lds_b + (wc * 64 + frow) * 32 + fk;
  for (int it = 0; it < kiters; ++it) {
    gld16(ga0, la0); gld16(ga1, la1);
    gld16(gb0, lb0); gld16(gb1, lb1);
    ga0 += 32; ga1 += 32; gb0 += 32; gb1 += 32;
    __syncthreads();
    short8 af[4], bfr[4];
#pragma unroll
    for (int i = 0; i < 4; ++i) af[i] = *(const short8*)(ra + i * 512);
#pragma unroll
    for (int j = 0; j < 4; ++j) bfr[j] = *(const short8*)(rb + j * 512);
#pragma unroll
    for (int i = 0; i < 4; ++i)
#pragma unroll
      for (int j = 0; j < 4; ++j)
        acc[i][j] = __builtin_amdgcn_mfma_f32_16x16x32_bf16(af[i], bfr[j], acc[i][j], 0, 0, 0);
    __syncthreads();
  }
}

// ---- 256x128 tile, BK=64, 512 thr (8 waves 4Mx2N, 64x64/wave). Unswizzled. LDS k-split:
// A [2][256][32] (32KB), B [2][128][32] (16KB); subtiles keep the proven 64B-row layout;
// gld16 dests linear, split via per-lane GLOBAL address permutation (rule #21). ----
DEVI void mfma_loop_256x128(const bf16* A, int ldA, const bf16* B, int ldB,
                            int kiters64, bf16* lds_a, bf16* lds_b, f32x4 acc[4][4])
{
  const int tid = threadIdx.x;       // 0..511
  const int lane = tid & 63;
  const int w = tid >> 6;            // 0..7
  const int wr = w >> 1, wc = w & 1; // wr 0..3 (M), wc 0..1 (N)
  const bf16* gA[4]; bf16* dA[4];
#pragma unroll
  for (int s = 0; s < 4; ++s) {
    const int p = s * 512 + tid;
    const int ksub = p >> 10;
    const int row = (p >> 2) & 255;
    const int c2 = p & 3;
    gA[s] = A + (size_t)row * ldA + ksub * 32 + c2 * 8;
    dA[s] = lds_a + p * 8;           // wave-uniform base + lane*16B
  }
  const bf16* gB[2]; bf16* dB[2];
#pragma unroll
  for (int s = 0; s < 2; ++s) {
    const int p = s * 512 + tid;
    const int ksub = p >> 9;
    const int row = (p >> 2) & 127;
    const int c2 = p & 3;
    gB[s] = B + (size_t)row * ldB + ksub * 32 + c2 * 8;
    dB[s] = lds_b + p * 8;
  }
  const int frow = lane & 15;
  const int fk = (lane >> 4) * 8;
  const bf16* ra = lds_a + (wr * 64 + frow) * 32 + fk;   // + kk*8192 + i*512
  const bf16* rb = lds_b + (wc * 64 + frow) * 32 + fk;   // + kk*4096 + j*512
  for (int it = 0; it < kiters64; ++it) {
#pragma unroll
    for (int s = 0; s < 4; ++s) gld16(gA[s], dA[s]);
#pragma unroll
    for (int s = 0; s < 2; ++s) gld16(gB[s], dB[s]);
#pragma unroll
    for (int s = 0; s < 4; ++s) gA[s] += 64;
#pragma unroll
    for (int s = 0; s < 2; ++s) gB[s] += 64;
    __syncthreads();
#pragma unroll
    for (int kk = 0; kk < 2; ++kk) {
      short8 af[4], bfr[4];
#pragma unroll
      for (int i = 0; i < 4; ++i) af[i] = *(const short8*)(ra + kk * 8192 + i * 512);
#pragma unroll
      for (int j = 0; j < 4; ++j) bfr[j] = *(const short8*)(rb + kk * 4096 + j * 512);
#pragma unroll
      for (int i = 0; i < 4; ++i)
#pragma unroll
        for (int j = 0; j < 4; ++j)
          acc[i][j] = __builtin_amdgcn_mfma_f32_16x16x32_bf16(af[i], bfr[j], acc[i][j], 0, 0, 0);
    }
    __syncthreads();
  }
}

#define ACC_INIT(acc)                                   \
  _Pragma("unroll") for (int i = 0; i < 4; ++i)         \
  _Pragma("unroll") for (int j = 0; j < 4; ++j)         \
      acc[i][j] = (f32x4){0.f, 0.f, 0.f, 0.f};

// ---- All fp32->bf16 casts in ONE launch + sums/sumsq zeroing block. ----
__global__ __launch_bounds__(256) void k_cast_all(
    const float* __restrict__ v, bf16* __restrict__ vbf,
    const float* __restrict__ s0, const float* __restrict__ s1,
    const float* __restrict__ s2, const float* __restrict__ s3,
    bf16* __restrict__ d0, bf16* __restrict__ d1,
    bf16* __restrict__ d2, bf16* __restrict__ d3,
    float* __restrict__ zbuf)
{
  const int bx = blockIdx.x;
  if (bx == 16384 + 512) {     // zero sums+sumsq: 2048 floats
    float4 z = {0.f, 0.f, 0.f, 0.f};
    *(float4*)(zbuf + threadIdx.x * 8) = z;
    *(float4*)(zbuf + threadIdx.x * 8 + 4) = z;
    return;
  }
  const float* in; bf16* out; size_t base;
  if (bx < 16384) {
    in = v; out = vbf; base = (size_t)bx * 2048;
  } else {
    const int wq = bx - 16384;
    switch (wq >> 7) {
      case 0:  in = s0; out = d0; break;
      case 1:  in = s1; out = d1; break;
      case 2:  in = s2; out = d2; break;
      default: in = s3; out = d3; break;
    }
    base = (size_t)(wq & 127) * 2048;
  }
  const size_t idx = base + (size_t)threadIdx.x * 8;
  float4 a = *(const float4*)(in + idx);
  float4 b = *(const float4*)(in + idx + 4);
  *(short8*)(out + idx) = cvt8(a, b);
}

// ---- Kernel A: projections, 256x128 tile. theta token-major; phi,g -> [b][ic][n].
// Both epilogues go through LDS for coalesced short8 stores. ----
__global__ __launch_bounds__(512) void k_proj(
    const bf16* __restrict__ vbf,
    const bf16* __restrict__ w_th, const float* __restrict__ b_th,
    const bf16* __restrict__ w_ph, const float* __restrict__ b_ph,
    const bf16* __restrict__ w_g,  const float* __restrict__ b_g,
    bf16* __restrict__ theta, bf16* __restrict__ phiT, bf16* __restrict__ gT)
{
  __shared__ __align__(16) char smem[49152];   // staging 48KB; epilogue reuses 34048B
  bf16* lds_a = (bf16*)smem;                   // [2][256][32] = 32KB
  bf16* lds_b = (bf16*)(smem + 32768);         // [2][128][32] = 16KB
  unsigned short* lds_t = (unsigned short*)smem;  // 128x133 repack buffer

  const int tt = blockIdx.x;        // token tile 0..127 (256 tokens each)
  const int yy = blockIdx.y;        // 0..5
  const int proj = yy >> 1;         // 0 theta, 1 phi, 2 g
  const int icb = (yy & 1) * 128;
  const bf16* wsel = (proj == 0) ? w_th : ((proj == 1) ? w_ph : w_g);
  const float* bsel = (proj == 0) ? b_th : ((proj == 1) ? b_ph : b_g);

  const size_t t0 = (size_t)tt * 256;
  f32x4 acc[4][4];
  ACC_INIT(acc);
  mfma_loop_256x128(vbf + t0 * 1024, 1024, wsel + (size_t)icb * 1024, 1024, 16,
                    lds_a, lds_b, acc);

  const int tid = threadIdx.x, lane = tid & 63, w = tid >> 6;
  const int wr = w >> 1, wc = w & 1, quad = lane >> 4, l15 = lane & 15;
  float biasv[4];
#pragma unroll
  for (int j = 0; j < 4; ++j) biasv[j] = bsel[icb + wc * 64 + j * 16 + l15];

  if (proj == 0) {
    // token-major: repack 2 x (128 x 128) halves -> coalesced short8 row stores
#pragma unroll
    for (int h = 0; h < 2; ++h) {
      __syncthreads();
      if ((wr >> 1) == h) {
#pragma unroll
        for (int i = 0; i < 4; ++i)
#pragma unroll
          for (int j = 0; j < 4; ++j)
#pragma unroll
            for (int r = 0; r < 4; ++r) {
              int mrow = (wr & 1) * 64 + i * 16 + quad * 4 + r;  // 0..127 within half
              int n = wc * 64 + j * 16 + l15;
              lds_t[mrow * 133 + n] = f2bf(acc[i][j][r] + biasv[j]);
            }
      }
      __syncthreads();
      const int r0 = tid >> 4;         // 0..31
      const int c0 = (tid & 15) * 8;   // 0..120
#pragma unroll
      for (int p = 0; p < 4; ++p) {
        int row = p * 32 + r0;
        short8 pk;
#pragma unroll
        for (int e = 0; e < 8; ++e) pk[e] = (short)lds_t[row * 133 + c0 + e];
        *(short8*)(theta + (t0 + h * 128 + row) * 256 + icb + c0) = pk;
      }
    }
  } else {
    bf16* outT = (proj == 1) ? phiT : gT;
    const int bb = (int)(t0 >> 12);
    const int n0 = (int)(t0 & 4095);
    const int tg = tid & 15;       // 16 token-groups x 8 tokens
    const int ch0 = tid >> 4;      // 0..31
#pragma unroll
    for (int h = 0; h < 2; ++h) {  // two 128-token halves share the 128x133 buffer
      __syncthreads();
      if ((wr >> 1) == h) {        // waves 0-3 own tokens 0..127; waves 4-7 own 128..255
#pragma unroll
        for (int i = 0; i < 4; ++i)
#pragma unroll
          for (int j = 0; j < 4; ++j)
#pragma unroll
            for (int r = 0; r < 4; ++r) {
              int mrow = (wr & 1) * 64 + i * 16 + quad * 4 + r;  // 0..127 within half
              int n = wc * 64 + j * 16 + l15;
              lds_t[mrow * 133 + n] = f2bf(acc[i][j][r] + biasv[j]);
            }
      }
      __syncthreads();
#pragma unroll
      for (int cc = 0; cc < 4; ++cc) {
        int ch = ch0 + cc * 32;
        short8 pk;
#pragma unroll
        for (int r = 0; r < 8; ++r) pk[r] = (short)lds_t[(tg * 8 + r) * 133 + ch];
        *(short8*)(outT + ((size_t)(bb * 256 + icb + ch)) * 4096 + n0 + h * 128 + tg * 8) = pk;
      }
    }
  }
}

// ---- Kernel B: Mp[kc][b] = phi[kc-chunk]^T g[kc-chunk], plain stores (atomic-free). ----
__global__ __launch_bounds__(256) void k_affin(
    const bf16* __restrict__ phiT, const bf16* __restrict__ gT, float* __restrict__ Mp)
{
  __shared__ __align__(16) char smem[16384];
  bf16* lds_a = (bf16*)smem;
  bf16* lds_b = (bf16*)(smem + 8192);
  const int kc = blockIdx.x;        // 0..7 K-chunk
  const int jt = blockIdx.y >> 1;   // 0..1
  const int it2 = blockIdx.y & 1;   // 0..1
  const int bb = blockIdx.z;        // 0..7
  f32x4 acc[4][4];
  ACC_INIT(acc);
  const bf16* A = phiT + ((size_t)bb * 256 + jt * 128) * 4096 + kc * 512;
  const bf16* B = gT   + ((size_t)bb * 256 + it2 * 128) * 4096 + kc * 512;
  mfma_loop(A, 4096, B, 4096, 16, lds_a, lds_b, acc);
  const int tid = threadIdx.x, lane = tid & 63, w = tid >> 6;
  const int wr = w >> 1, wc = w & 1, quad = lane >> 4, l15 = lane & 15;
  float* Mb = Mp + ((size_t)kc * 8 + bb) * 65536;
#pragma unroll
  for (int i = 0; i < 4; ++i)
#pragma unroll
    for (int j = 0; j < 4; ++j)
#pragma unroll
      for (int r = 0; r < 4; ++r) {
        int m = wr * 64 + i * 16 + quad * 4 + r;
        int n = wc * 64 + j * 16 + l15;
        Mb[(size_t)(jt * 128 + m) * 256 + it2 * 128 + n] = acc[i][j][r];
      }
}

// ---- Reduce 8 kc-partials -> bf16, folding the 1/N affinity normalization. ----
__global__ __launch_bounds__(256) void k_mconv(const float* __restrict__ Mp, bf16* __restrict__ Mbf)
{
  const size_t i = ((size_t)blockIdx.x * 256 + threadIdx.x) * 4;   // 524288 elems / 4
  float4 s = *(const float4*)(Mp + i);
#pragma unroll
  for (int kc = 1; kc < 8; ++kc) {
    float4 p = *(const float4*)(Mp + (size_t)kc * 524288 + i);
    s.x += p.x; s.y += p.y; s.z += p.z; s.w += p.w;
  }
  short4v o;
  o[0] = (short)f2bf(s.x * (1.0f / 4096.0f));
  o[1] = (short)f2bf(s.y * (1.0f / 4096.0f));
  o[2] = (short)f2bf(s.z * (1.0f / 4096.0f));
  o[3] = (short)f2bf(s.w * (1.0f / 4096.0f));
  *(short4v*)(Mbf + i) = o;
}

// ---- Kernel C: PT[b][c][j] = sum_i W_w[c][i] * Mbf[b][j][i]. ----
__global__ __launch_bounds__(256) void k_pt(
    const bf16* __restrict__ Ww, const bf16* __restrict__ Mbf, bf16* __restrict__ PT)
{
  __shared__ __align__(16) char smem[16384];
  bf16* lds_a = (bf16*)smem;
  bf16* lds_b = (bf16*)(smem + 8192);
  const int ct = blockIdx.x;   // 0..7
  const int jt = blockIdx.y;   // 0..1
  const int bb = blockIdx.z;   // 0..7
  f32x4 acc[4][4];
  ACC_INIT(acc);
  mfma_loop(Ww + (size_t)ct * 128 * 256, 256,
            Mbf + ((size_t)bb * 256 + jt * 128) * 256, 256, 8, lds_a, lds_b, acc);
  const int tid = threadIdx.x, lane = tid & 63, w = tid >> 6;
  const int wr = w >> 1, wc = w & 1, quad = lane >> 4, l15 = lane & 15;
#pragma unroll
  for (int i = 0; i < 4; ++i)
#pragma unroll
    for (int j = 0; j < 4; ++j)
#pragma unroll
      for (int r = 0; r < 4; ++r) {
        int m = wr * 64 + i * 16 + quad * 4 + r;
        int n = wc * 64 + j * 16 + l15;
        PT[((size_t)bb * 1024 + ct * 128 + m) * 256 + jt * 128 + n] = __float2bfloat16(acc[i][j][r]);
      }
}

// ---- Kernel D: Wy[t][c] = sum_j theta[t][j] * PT[b][c][j], 256x128 tile / 512 thr.
// Epilogue: LDS repack -> coalesced short8 Wy stores; BN stats from regs (quad-shfl ->
// cross-wave LDS reduce -> 1 atomic per channel per block). ----
__global__ __launch_bounds__(512) void k_wy(
    const bf16* __restrict__ theta, const bf16* __restrict__ PT, bf16* __restrict__ Wy,
    float* __restrict__ sums, float* __restrict__ sumsq)
{
  __shared__ __align__(16) char smem[49152];   // staging 48KB; epilogue reuses 34048B
  bf16* lds_a = (bf16*)smem;                   // [2][256][32]
  bf16* lds_b = (bf16*)(smem + 32768);         // [2][128][32]
  unsigned short* lds_t = (unsigned short*)smem;  // 128x133 repack buffer
  const size_t t0 = (size_t)blockIdx.x * 256;  // token tile (128 tiles)
  const int ct = blockIdx.y;                   // 0..7
  const int bb = (int)(t0 >> 12);
  f32x4 acc[4][4];
  ACC_INIT(acc);
  mfma_loop_256x128(theta + t0 * 256, 256,
                    PT + ((size_t)bb * 1024 + ct * 128) * 256, 256, 4, lds_a, lds_b, acc);
  const int tid = threadIdx.x, lane = tid & 63, w = tid >> 6;
  const int wr = w >> 1, wc = w & 1, quad = lane >> 4, l15 = lane & 15;
  // stats partials from registers (independent of the repack below)
  float ps[4] = {0.f, 0.f, 0.f, 0.f}, pq[4] = {0.f, 0.f, 0.f, 0.f};
#pragma unroll
  for (int i = 0; i < 4; ++i)
#pragma unroll
    for (int j = 0; j < 4; ++j)
#pragma unroll
      for (int r = 0; r < 4; ++r) {
        float f = acc[i][j][r];
        ps[j] += f; pq[j] += f * f;
      }
#pragma unroll
  for (int j = 0; j < 4; ++j) {
    ps[j] += __shfl_xor(ps[j], 16); ps[j] += __shfl_xor(ps[j], 32);
    pq[j] += __shfl_xor(pq[j], 16); pq[j] += __shfl_xor(pq[j], 32);
  }
  // Wy store via LDS repack, 2 x (128 x 128) halves
#pragma unroll
  for (int h = 0; h < 2; ++h) {
    __syncthreads();
    if ((wr >> 1) == h) {
#pragma unroll
      for (int i = 0; i < 4; ++i)
#pragma unroll
        for (int j = 0; j < 4; ++j)
#pragma unroll
          for (int r = 0; r < 4; ++r) {
            int mrow = (wr & 1) * 64 + i * 16 + quad * 4 + r;
            int n = wc * 64 + j * 16 + l15;
            lds_t[mrow * 133 + n] = f2bf(acc[i][j][r]);
          }
    }
    __syncthreads();
    const int r0 = tid >> 4;
    const int c0 = (tid & 15) * 8;
#pragma unroll
    for (int p = 0; p < 4; ++p) {
      int row = p * 32 + r0;
      short8 pk;
#pragma unroll
      for (int e = 0; e < 8; ++e) pk[e] = (short)lds_t[row * 133 + c0 + e];
      *(short8*)(Wy + (t0 + h * 128 + row) * 1024 + ct * 128 + c0) = pk;
    }
  }
  // cross-wave stats reduce (reuse LDS after repack reads are done)
  __syncthreads();
  float* sred = (float*)smem;
  float* sqred = sred + 512;
  if (quad == 0) {
#pragma unroll
    for (int j = 0; j < 4; ++j) {
      sred[w * 64 + j * 16 + l15] = ps[j];
      sqred[w * 64 + j * 16 + l15] = pq[j];
    }
  }
  __syncthreads();
  if (tid < 128) {                       // sums: 2 wc x 64 ch
    const int wc2 = tid >> 6, ch = tid & 63;
    float s = sred[(wc2 + 0) * 64 + ch] + sred[(wc2 + 2) * 64 + ch]
            + sred[(wc2 + 4) * 64 + ch] + sred[(wc2 + 6) * 64 + ch];
    atomicAdd(&sums[ct * 128 + wc2 * 64 + ch], s);
  } else if (tid < 256) {                // sumsq
    const int t2 = tid - 128;
    const int wc2 = t2 >> 6, ch = t2 & 63;
    float q = sqred[(wc2 + 0) * 64 + ch] + sqred[(wc2 + 2) * 64 + ch]
            + sqred[(wc2 + 4) * 64 + ch] + sqred[(wc2 + 6) * 64 + ch];
    atomicAdd(&sumsq[ct * 128 + wc2 * 64 + ch], q);
  }
}

// ---- Output: BN affine inline; residual from vbf (bf16) -- v fp32 no longer read. ----
__global__ __launch_bounds__(256) void k_out(const bf16* __restrict__ Wy, const bf16* __restrict__ vbf,
                                             const float* __restrict__ sums, const float* __restrict__ sumsq,
                                             const float* __restrict__ gamma, const float* __restrict__ beta,
                                             float* __restrict__ out)
{
  const size_t idx = ((size_t)blockIdx.x * 256 + threadIdx.x) * 4;
  const int c = (int)(idx & 1023);
  float4 sm = *(const float4*)(sums + c);
  float4 sq = *(const float4*)(sumsq + c);
  float4 gm = *(const float4*)(gamma + c);
  float4 bt = *(const float4*)(beta + c);
  short4v wv = *(const short4v*)(Wy + idx);
  short4v vv = *(const short4v*)(vbf + idx);
  float4 o;
#pragma unroll
  for (int k = 0; k < 4; ++k) {
    float smk = (&sm.x)[k], sqk = (&sq.x)[k], gmk = (&gm.x)[k], btk = (&bt.x)[k];
    float mean = smk * (1.0f / 32768.0f);
    float var = sqk * (1.0f / 32768.0f) - mean * mean;
    float sc = gmk * rsqrtf(var + 1e-5f);
    float sh = btk - mean * sc;
    (&o.x)[k] = bf2f((unsigned short)wv[k]) * sc + sh + bf2f((unsigned short)vv[k]);
  }
  *(float4*)(out + idx) = o;
}

extern "C" void kernel_launch(void* const* d_in, const int* in_sizes, int n_in,
                              void* d_out, int out_size, void* d_ws, size_t ws_size,
                              hipStream_t stream)
{
  (void)in_sizes; (void)n_in; (void)out_size; (void)ws_size;
  const float* v    = (const float*)d_in[0];
  const float* g_w  = (const float*)d_in[1];
  const float* g_b  = (const float*)d_in[2];
  const float* th_w = (const float*)d_in[3];
  const float* th_b = (const float*)d_in[4];
  const float* ph_w = (const float*)d_in[5];
  const float* ph_b = (const float*)d_in[6];
  const float* W_w  = (const float*)d_in[7];
  // d_in[8] = W_b: per-channel constant, exactly cancelled by BatchNorm mean. Unused.
  const float* gamma = (const float*)d_in[9];
  const float* beta  = (const float*)d_in[10];
  float* out = (float*)d_out;

  char* ws = (char*)d_ws;
  bf16* vbf  = (bf16*)ws;   ws += (size_t)32768 * 1024 * 2;   // 64 MiB, live until k_out
  bf16* Wy   = (bf16*)ws;   ws += (size_t)32768 * 1024 * 2;   // 64 MiB (un-aliased)
  bf16* theta = (bf16*)ws;  ws += (size_t)32768 * 256 * 2;    // 16 MiB
  bf16* phiT  = (bf16*)ws;  ws += (size_t)32768 * 256 * 2;    // 16 MiB
  bf16* gT    = (bf16*)ws;  ws += (size_t)32768 * 256 * 2;    // 16 MiB
  float* Mp   = (float*)ws; ws += (size_t)8 * 524288 * 4;     // 16 MiB (un-aliased)
  bf16* Mbf   = (bf16*)ws;  ws += (size_t)8 * 65536 * 2;      // 1 MiB
  bf16* PT    = (bf16*)ws;  ws += (size_t)8 * 1024 * 256 * 2; // 4 MiB
  bf16* thwb  = (bf16*)ws;  ws += (size_t)256 * 1024 * 2;
  bf16* phwb  = (bf16*)ws;  ws += (size_t)256 * 1024 * 2;
  bf16* gwb   = (bf16*)ws;  ws += (size_t)256 * 1024 * 2;
  bf16* Wwb   = (bf16*)ws;  ws += (size_t)1024 * 256 * 2;
  float* sums = (float*)ws; ws += 4096;
  float* sumsq= (float*)ws; ws += 4096;

  k_cast_all<<<16384 + 512 + 1, 256, 0, stream>>>(v, vbf, th_w, ph_w, g_w, W_w,
                                                  thwb, phwb, gwb, Wwb, sums);

  k_proj <<<dim3(128, 6), 512, 0, stream>>>(vbf, thwb, th_b, phwb, ph_b, gwb, g_b, theta, phiT, gT);
  k_affin<<<dim3(8, 4, 8), 256, 0, stream>>>(phiT, gT, Mp);
  k_mconv<<<512, 256, 0, stream>>>(Mp, Mbf);
  k_pt   <<<dim3(8, 2, 8), 256, 0, stream>>>(Wwb, Mbf, PT);
  k_wy   <<<dim3(128, 8), 512, 0, stream>>>(theta, PT, Wy, sums, sumsq);
  k_out  <<<32768, 256, 0, stream>>>(Wy, vbf, sums, sumsq, gamma, beta, out);
}

// Round 10
// 401.735 us; speedup vs baseline: 1.0500x; 1.0500x over previous
//
#include <hip/hip_runtime.h>
#include <hip/hip_bf16.h>
#include <stdint.h>

// Rs_GCN fused pipeline, MI355X (gfx950).
// Algebra: y = (theta phi^T /N) g  ==  theta @ (phi^T g)/N  (no softmax -> associativity).
// W_y = theta @ P, P = (phi^T g) W_w^T / N.  W_b dropped (exact under BatchNorm).
// R10 = R8 (best measured, 416.0us) + k_out residual from vbf (bf16, -64 MiB read;
// numerics validated in R9: absmax unchanged). R9's LDS-repack epilogues REVERTED:
// direct scalar stores from registers beat barrier-ordered LDS repack (R9: +6us net --
// scattered 2B stores overlap with MFMA waves and L2 write-combining absorbs them).
// Workspace: vbf live to end; Mp aliases Wy slab (Mp dead before k_wy writes Wy).
// Floors: fill ~78/iter (harness re-poison, 86% HBM peak), cast ~31 (roofline),
// proj ~60 (2-barrier ceiling @ K=1024; 8-phase is a wash at this K per m248),
// out ~42 after this round, affin/mconv/pt ~20, wy ~20.

using bf16 = __hip_bfloat16;
typedef __attribute__((ext_vector_type(8))) short short8;
typedef __attribute__((ext_vector_type(4))) float f32x4;
typedef __attribute__((ext_vector_type(4))) short short4v;

#define DEVI static __device__ __forceinline__

DEVI float bf2f(unsigned short u) {
  union { unsigned int i; float f; } x; x.i = ((unsigned int)u) << 16; return x.f;
}
DEVI unsigned short f2bf(float f) {
  __hip_bfloat16 h = __float2bfloat16(f);
  return *reinterpret_cast<unsigned short*>(&h);
}

DEVI void gld16(const void* g, void* l) {
  __builtin_amdgcn_global_load_lds((__attribute__((address_space(1))) void*)g,
                                   (__attribute__((address_space(3))) void*)l,
                                   16, 0, 0);
}

DEVI short8 cvt8(float4 a, float4 b) {
  short8 o;
  o[0] = (short)f2bf(a.x); o[1] = (short)f2bf(a.y);
  o[2] = (short)f2bf(a.z); o[3] = (short)f2bf(a.w);
  o[4] = (short)f2bf(b.x); o[5] = (short)f2bf(b.y);
  o[6] = (short)f2bf(b.z); o[7] = (short)f2bf(b.w);
  return o;
}

// ---- 128x128 tile, BK=32, 256 thr (4 waves 2x2). Swizzled LDS (conflict-free ds_read,
// measured R3); used by short-K kernels k_affin/k_pt. ----
DEVI void mfma_loop(const bf16* A, int ldA, const bf16* B, int ldB,
                    int kiters, bf16* lds_a, bf16* lds_b, f32x4 acc[4][4])
{
  const int tid = threadIdx.x;
  const int lane = tid & 63;
  const int w = tid >> 6;
  const int wr = w >> 1, wc = w & 1;
  const int srow = w * 32 + (lane >> 2);
  const int scol = (((lane & 3) ^ ((srow >> 1) & 3))) * 8;   // source-side swizzle
  const bf16* ga0 = A + (size_t)srow * ldA + scol;
  const bf16* ga1 = A + (size_t)(srow + 16) * ldA + scol;
  const bf16* gb0 = B + (size_t)srow * ldB + scol;
  const bf16* gb1 = B + (size_t)(srow + 16) * ldB + scol;
  bf16* la0 = lds_a + w * 1024 + lane * 8;
  bf16* la1 = la0 + 512;
  bf16* lb0 = lds_b + w * 1024 + lane * 8;
  bf16* lb1 = lb0 + 512;
  const int frow = lane & 15;
  const int fk = (((lane >> 4) ^ ((frow >> 1) & 3))) * 8;    // read-side swizzle (same XOR)
  const bf16* ra = lds_a + (wr * 64 + frow) * 32 + fk;
  const bf16* rb = lds_b + (wc * 64 + frow) * 32 + fk;
  for (int it = 0; it < kiters; ++it) {
    gld16(ga0, la0); gld16(ga1, la1);
    gld16(gb0, lb0); gld16(gb1, lb1);
    ga0 += 32; ga1 += 32; gb0 += 32; gb1 += 32;
    __syncthreads();
    short8 af[4], bfr[4];
#pragma unroll
    for (int i = 0; i < 4; ++i) af[i] = *(const short8*)(ra + i * 512);
#pragma unroll
    for (int j = 0; j < 4; ++j) bfr[j] = *(const short8*)(rb + j * 512);
#pragma unroll
    for (int i = 0; i < 4; ++i)
#pragma unroll
      for (int j = 0; j < 4; ++j)
        acc[i][j] = __builtin_amdgcn_mfma_f32_16x16x32_bf16(af[i], bfr[j], acc[i][j], 0, 0, 0);
    __syncthreads();
  }
}

// ---- 256x128 tile, BK=64, 512 thr (8 waves 4Mx2N, 64x64/wave). Unswizzled. LDS k-split:
// A [2][256][32] (32KB), B [2][128][32] (16KB); subtiles keep the proven 64B-row layout;
// gld16 dests linear, split via per-lane GLOBAL address permutation (rule #21). ----
DEVI void mfma_loop_256x128(const bf16* A, int ldA, const bf16* B, int ldB,
                            int kiters64, bf16* lds_a, bf16* lds_b, f32x4 acc[4][4])
{
  const int tid = threadIdx.x;       // 0..511
  const int lane = tid & 63;
  const int w = tid >> 6;            // 0..7
  const int wr = w >> 1, wc = w & 1; // wr 0..3 (M), wc 0..1 (N)
  const bf16* gA[4]; bf16* dA[4];
#pragma unroll
  for (int s = 0; s < 4; ++s) {
    const int p = s * 512 + tid;
    const int ksub = p >> 10;
    const int row = (p >> 2) & 255;
    const int c2 = p & 3;
    gA[s] = A + (size_t)row * ldA + ksub * 32 + c2 * 8;
    dA[s] = lds_a + p * 8;           // wave-uniform base + lane*16B
  }
  const bf16* gB[2]; bf16* dB[2];
#pragma unroll
  for (int s = 0; s < 2; ++s) {
    const int p = s * 512 + tid;
    const int ksub = p >> 9;
    const int row = (p >> 2) & 127;
    const int c2 = p & 3;
    gB[s] = B + (size_t)row * ldB + ksub * 32 + c2 * 8;
    dB[s] = lds_b + p * 8;
  }
  const int frow = lane & 15;
  const int fk = (lane >> 4) * 8;
  const bf16* ra = lds_a + (wr * 64 + frow) * 32 + fk;   // + kk*8192 + i*512
  const bf16* rb = lds_b + (wc * 64 + frow) * 32 + fk;   // + kk*4096 + j*512
  for (int it = 0; it < kiters64; ++it) {
#pragma unroll
    for (int s = 0; s < 4; ++s) gld16(gA[s], dA[s]);
#pragma unroll
    for (int s = 0; s < 2; ++s) gld16(gB[s], dB[s]);
#pragma unroll
    for (int s = 0; s < 4; ++s) gA[s] += 64;
#pragma unroll
    for (int s = 0; s < 2; ++s) gB[s] += 64;
    __syncthreads();
#pragma unroll
    for (int kk = 0; kk < 2; ++kk) {
      short8 af[4], bfr[4];
#pragma unroll
      for (int i = 0; i < 4; ++i) af[i] = *(const short8*)(ra + kk * 8192 + i * 512);
#pragma unroll
      for (int j = 0; j < 4; ++j) bfr[j] = *(const short8*)(rb + kk * 4096 + j * 512);
#pragma unroll
      for (int i = 0; i < 4; ++i)
#pragma unroll
        for (int j = 0; j < 4; ++j)
          acc[i][j] = __builtin_amdgcn_mfma_f32_16x16x32_bf16(af[i], bfr[j], acc[i][j], 0, 0, 0);
    }
    __syncthreads();
  }
}

#define ACC_INIT(acc)                                   \
  _Pragma("unroll") for (int i = 0; i < 4; ++i)         \
  _Pragma("unroll") for (int j = 0; j < 4; ++j)         \
      acc[i][j] = (f32x4){0.f, 0.f, 0.f, 0.f};

// ---- All fp32->bf16 casts in ONE launch + sums/sumsq zeroing block. ----
__global__ __launch_bounds__(256) void k_cast_all(
    const float* __restrict__ v, bf16* __restrict__ vbf,
    const float* __restrict__ s0, const float* __restrict__ s1,
    const float* __restrict__ s2, const float* __restrict__ s3,
    bf16* __restrict__ d0, bf16* __restrict__ d1,
    bf16* __restrict__ d2, bf16* __restrict__ d3,
    float* __restrict__ zbuf)
{
  const int bx = blockIdx.x;
  if (bx == 16384 + 512) {     // zero sums+sumsq: 2048 floats
    float4 z = {0.f, 0.f, 0.f, 0.f};
    *(float4*)(zbuf + threadIdx.x * 8) = z;
    *(float4*)(zbuf + threadIdx.x * 8 + 4) = z;
    return;
  }
  const float* in; bf16* out; size_t base;
  if (bx < 16384) {
    in = v; out = vbf; base = (size_t)bx * 2048;
  } else {
    const int wq = bx - 16384;
    switch (wq >> 7) {
      case 0:  in = s0; out = d0; break;
      case 1:  in = s1; out = d1; break;
      case 2:  in = s2; out = d2; break;
      default: in = s3; out = d3; break;
    }
    base = (size_t)(wq & 127) * 2048;
  }
  const size_t idx = base + (size_t)threadIdx.x * 8;
  float4 a = *(const float4*)(in + idx);
  float4 b = *(const float4*)(in + idx + 4);
  *(short8*)(out + idx) = cvt8(a, b);
}

// ---- Kernel A: projections, 256x128 tile. theta token-major (direct stores, R8 form);
// phi,g transposed [b][ic][n] via LDS transpose epilogue. ----
__global__ __launch_bounds__(512) void k_proj(
    const bf16* __restrict__ vbf,
    const bf16* __restrict__ w_th, const float* __restrict__ b_th,
    const bf16* __restrict__ w_ph, const float* __restrict__ b_ph,
    const bf16* __restrict__ w_g,  const float* __restrict__ b_g,
    bf16* __restrict__ theta, bf16* __restrict__ phiT, bf16* __restrict__ gT)
{
  __shared__ __align__(16) char smem[49152];   // staging 48KB; epilogue reuses 34048B
  bf16* lds_a = (bf16*)smem;                   // [2][256][32] = 32KB
  bf16* lds_b = (bf16*)(smem + 32768);         // [2][128][32] = 16KB
  unsigned short* lds_t = (unsigned short*)smem;  // 128x133 transpose buffer

  const int tt = blockIdx.x;        // token tile 0..127 (256 tokens each)
  const int yy = blockIdx.y;        // 0..5
  const int proj = yy >> 1;         // 0 theta, 1 phi, 2 g
  const int icb = (yy & 1) * 128;
  const bf16* wsel = (proj == 0) ? w_th : ((proj == 1) ? w_ph : w_g);
  const float* bsel = (proj == 0) ? b_th : ((proj == 1) ? b_ph : b_g);

  const size_t t0 = (size_t)tt * 256;
  f32x4 acc[4][4];
  ACC_INIT(acc);
  mfma_loop_256x128(vbf + t0 * 1024, 1024, wsel + (size_t)icb * 1024, 1024, 16,
                    lds_a, lds_b, acc);

  const int tid = threadIdx.x, lane = tid & 63, w = tid >> 6;
  const int wr = w >> 1, wc = w & 1, quad = lane >> 4, l15 = lane & 15;
  float biasv[4];
#pragma unroll
  for (int j = 0; j < 4; ++j) biasv[j] = bsel[icb + wc * 64 + j * 16 + l15];

  if (proj == 0) {
#pragma unroll
    for (int i = 0; i < 4; ++i)
#pragma unroll
      for (int j = 0; j < 4; ++j)
#pragma unroll
        for (int r = 0; r < 4; ++r) {
          int m = wr * 64 + i * 16 + quad * 4 + r;       // 0..255
          int n = wc * 64 + j * 16 + l15;                // 0..127
          theta[(t0 + m) * 256 + icb + n] = __float2bfloat16(acc[i][j][r] + biasv[j]);
        }
  } else {
    bf16* outT = (proj == 1) ? phiT : gT;
    const int bb = (int)(t0 >> 12);
    const int n0 = (int)(t0 & 4095);
    const int tg = tid & 15;       // 16 token-groups x 8 tokens
    const int ch0 = tid >> 4;      // 0..31
#pragma unroll
    for (int h = 0; h < 2; ++h) {  // two 128-token halves share the 128x133 buffer
      __syncthreads();
      if ((wr >> 1) == h) {        // waves 0-3 own tokens 0..127; waves 4-7 own 128..255
#pragma unroll
        for (int i = 0; i < 4; ++i)
#pragma unroll
          for (int j = 0; j < 4; ++j)
#pragma unroll
            for (int r = 0; r < 4; ++r) {
              int mrow = (wr & 1) * 64 + i * 16 + quad * 4 + r;  // 0..127 within half
              int n = wc * 64 + j * 16 + l15;
              lds_t[mrow * 133 + n] = f2bf(acc[i][j][r] + biasv[j]);
            }
      }
      __syncthreads();
#pragma unroll
      for (int cc = 0; cc < 4; ++cc) {
        int ch = ch0 + cc * 32;
        short8 pk;
#pragma unroll
        for (int r = 0; r < 8; ++r) pk[r] = (short)lds_t[(tg * 8 + r) * 133 + ch];
        *(short8*)(outT + ((size_t)(bb * 256 + icb + ch)) * 4096 + n0 + h * 128 + tg * 8) = pk;
      }
    }
  }
}

// ---- Kernel B: Mp[kc][b] = phi[kc-chunk]^T g[kc-chunk], plain stores (atomic-free). ----
__global__ __launch_bounds__(256) void k_affin(
    const bf16* __restrict__ phiT, const bf16* __restrict__ gT, float* __restrict__ Mp)
{
  __shared__ __align__(16) char smem[16384];
  bf16* lds_a = (bf16*)smem;
  bf16* lds_b = (bf16*)(smem + 8192);
  const int kc = blockIdx.x;        // 0..7 K-chunk
  const int jt = blockIdx.y >> 1;   // 0..1
  const int it2 = blockIdx.y & 1;   // 0..1
  const int bb = blockIdx.z;        // 0..7
  f32x4 acc[4][4];
  ACC_INIT(acc);
  const bf16* A = phiT + ((size_t)bb * 256 + jt * 128) * 4096 + kc * 512;
  const bf16* B = gT   + ((size_t)bb * 256 + it2 * 128) * 4096 + kc * 512;
  mfma_loop(A, 4096, B, 4096, 16, lds_a, lds_b, acc);
  const int tid = threadIdx.x, lane = tid & 63, w = tid >> 6;
  const int wr = w >> 1, wc = w & 1, quad = lane >> 4, l15 = lane & 15;
  float* Mb = Mp + ((size_t)kc * 8 + bb) * 65536;
#pragma unroll
  for (int i = 0; i < 4; ++i)
#pragma unroll
    for (int j = 0; j < 4; ++j)
#pragma unroll
      for (int r = 0; r < 4; ++r) {
        int m = wr * 64 + i * 16 + quad * 4 + r;
        int n = wc * 64 + j * 16 + l15;
        Mb[(size_t)(jt * 128 + m) * 256 + it2 * 128 + n] = acc[i][j][r];
      }
}

// ---- Reduce 8 kc-partials -> bf16, folding the 1/N affinity normalization. ----
__global__ __launch_bounds__(256) void k_mconv(const float* __restrict__ Mp, bf16* __restrict__ Mbf)
{
  const size_t i = ((size_t)blockIdx.x * 256 + threadIdx.x) * 4;   // 524288 elems / 4
  float4 s = *(const float4*)(Mp + i);
#pragma unroll
  for (int kc = 1; kc < 8; ++kc) {
    float4 p = *(const float4*)(Mp + (size_t)kc * 524288 + i);
    s.x += p.x; s.y += p.y; s.z += p.z; s.w += p.w;
  }
  short4v o;
  o[0] = (short)f2bf(s.x * (1.0f / 4096.0f));
  o[1] = (short)f2bf(s.y * (1.0f / 4096.0f));
  o[2] = (short)f2bf(s.z * (1.0f / 4096.0f));
  o[3] = (short)f2bf(s.w * (1.0f / 4096.0f));
  *(short4v*)(Mbf + i) = o;
}

// ---- Kernel C: PT[b][c][j] = sum_i W_w[c][i] * Mbf[b][j][i]. ----
__global__ __launch_bounds__(256) void k_pt(
    const bf16* __restrict__ Ww, const bf16* __restrict__ Mbf, bf16* __restrict__ PT)
{
  __shared__ __align__(16) char smem[16384];
  bf16* lds_a = (bf16*)smem;
  bf16* lds_b = (bf16*)(smem + 8192);
  const int ct = blockIdx.x;   // 0..7
  const int jt = blockIdx.y;   // 0..1
  const int bb = blockIdx.z;   // 0..7
  f32x4 acc[4][4];
  ACC_INIT(acc);
  mfma_loop(Ww + (size_t)ct * 128 * 256, 256,
            Mbf + ((size_t)bb * 256 + jt * 128) * 256, 256, 8, lds_a, lds_b, acc);
  const int tid = threadIdx.x, lane = tid & 63, w = tid >> 6;
  const int wr = w >> 1, wc = w & 1, quad = lane >> 4, l15 = lane & 15;
#pragma unroll
  for (int i = 0; i < 4; ++i)
#pragma unroll
    for (int j = 0; j < 4; ++j)
#pragma unroll
      for (int r = 0; r < 4; ++r) {
        int m = wr * 64 + i * 16 + quad * 4 + r;
        int n = wc * 64 + j * 16 + l15;
        PT[((size_t)bb * 1024 + ct * 128 + m) * 256 + jt * 128 + n] = __float2bfloat16(acc[i][j][r]);
      }
}

// ---- Kernel D: Wy[t][c] = sum_j theta[t][j] * PT[b][c][j], 256x128 tile / 512 thr.
// Direct scalar stores (R8 form); BN stats fused: quad-shfl -> cross-wave LDS reduce ->
// 1 atomic per channel per block. ----
__global__ __launch_bounds__(512) void k_wy(
    const bf16* __restrict__ theta, const bf16* __restrict__ PT, bf16* __restrict__ Wy,
    float* __restrict__ sums, float* __restrict__ sumsq)
{
  __shared__ __align__(16) char smem[49152];   // staging 48KB; stats reduce reuses 4KB
  bf16* lds_a = (bf16*)smem;                   // [2][256][32]
  bf16* lds_b = (bf16*)(smem + 32768);         // [2][128][32]
  const size_t t0 = (size_t)blockIdx.x * 256;  // token tile (128 tiles)
  const int ct = blockIdx.y;                   // 0..7
  const int bb = (int)(t0 >> 12);
  f32x4 acc[4][4];
  ACC_INIT(acc);
  mfma_loop_256x128(theta + t0 * 256, 256,
                    PT + ((size_t)bb * 1024 + ct * 128) * 256, 256, 4, lds_a, lds_b, acc);
  const int tid = threadIdx.x, lane = tid & 63, w = tid >> 6;
  const int wr = w >> 1, wc = w & 1, quad = lane >> 4, l15 = lane & 15;
  float ps[4] = {0.f, 0.f, 0.f, 0.f}, pq[4] = {0.f, 0.f, 0.f, 0.f};
#pragma unroll
  for (int i = 0; i < 4; ++i)
#pragma unroll
    for (int j = 0; j < 4; ++j)
#pragma unroll
      for (int r = 0; r < 4; ++r) {
        int m = wr * 64 + i * 16 + quad * 4 + r;   // 0..255
        int n = wc * 64 + j * 16 + l15;            // 0..127
        float f = acc[i][j][r];
        Wy[(t0 + m) * 1024 + ct * 128 + n] = __float2bfloat16(f);
        ps[j] += f; pq[j] += f * f;
      }
  // quad-reduce: lanes {l15, +16, +32, +48} hold partials for the same channel
#pragma unroll
  for (int j = 0; j < 4; ++j) {
    ps[j] += __shfl_xor(ps[j], 16); ps[j] += __shfl_xor(ps[j], 32);
    pq[j] += __shfl_xor(pq[j], 16); pq[j] += __shfl_xor(pq[j], 32);
  }
  // cross-wave reduce in (dead staging) LDS: sred/sqred [8 waves][64 channels]
  float* sred = (float*)smem;
  float* sqred = sred + 512;
  __syncthreads();
  if (quad == 0) {
#pragma unroll
    for (int j = 0; j < 4; ++j) {
      sred[w * 64 + j * 16 + l15] = ps[j];
      sqred[w * 64 + j * 16 + l15] = pq[j];
    }
  }
  __syncthreads();
  if (tid < 128) {                       // sums: 2 wc x 64 ch
    const int wc2 = tid >> 6, ch = tid & 63;
    float s = sred[(wc2 + 0) * 64 + ch] + sred[(wc2 + 2) * 64 + ch]
            + sred[(wc2 + 4) * 64 + ch] + sred[(wc2 + 6) * 64 + ch];
    atomicAdd(&sums[ct * 128 + wc2 * 64 + ch], s);
  } else if (tid < 256) {                // sumsq
    const int t2 = tid - 128;
    const int wc2 = t2 >> 6, ch = t2 & 63;
    float q = sqred[(wc2 + 0) * 64 + ch] + sqred[(wc2 + 2) * 64 + ch]
            + sqred[(wc2 + 4) * 64 + ch] + sqred[(wc2 + 6) * 64 + ch];
    atomicAdd(&sumsq[ct * 128 + wc2 * 64 + ch], q);
  }
}

// ---- Output: BN affine inline; residual from vbf (bf16) -- v fp32 no longer read. ----
__global__ __launch_bounds__(256) void k_out(const bf16* __restrict__ Wy, const bf16* __restrict__ vbf,
                                             const float* __restrict__ sums, const float* __restrict__ sumsq,
                                             const float* __restrict__ gamma, const float* __restrict__ beta,
                                             float* __restrict__ out)
{
  const size_t idx = ((size_t)blockIdx.x * 256 + threadIdx.x) * 4;
  const int c = (int)(idx & 1023);
  float4 sm = *(const float4*)(sums + c);
  float4 sq = *(const float4*)(sumsq + c);
  float4 gm = *(const float4*)(gamma + c);
  float4 bt = *(const float4*)(beta + c);
  short4v wv = *(const short4v*)(Wy + idx);
  short4v vv = *(const short4v*)(vbf + idx);
  float4 o;
#pragma unroll
  for (int k = 0; k < 4; ++k) {
    float smk = (&sm.x)[k], sqk = (&sq.x)[k], gmk = (&gm.x)[k], btk = (&bt.x)[k];
    float mean = smk * (1.0f / 32768.0f);
    float var = sqk * (1.0f / 32768.0f) - mean * mean;
    float sc = gmk * rsqrtf(var + 1e-5f);
    float sh = btk - mean * sc;
    (&o.x)[k] = bf2f((unsigned short)wv[k]) * sc + sh + bf2f((unsigned short)vv[k]);
  }
  *(float4*)(out + idx) = o;
}

extern "C" void kernel_launch(void* const* d_in, const int* in_sizes, int n_in,
                              void* d_out, int out_size, void* d_ws, size_t ws_size,
                              hipStream_t stream)
{
  (void)in_sizes; (void)n_in; (void)out_size; (void)ws_size;
  const float* v    = (const float*)d_in[0];
  const float* g_w  = (const float*)d_in[1];
  const float* g_b  = (const float*)d_in[2];
  const float* th_w = (const float*)d_in[3];
  const float* th_b = (const float*)d_in[4];
  const float* ph_w = (const float*)d_in[5];
  const float* ph_b = (const float*)d_in[6];
  const float* W_w  = (const float*)d_in[7];
  // d_in[8] = W_b: per-channel constant, exactly cancelled by BatchNorm mean. Unused.
  const float* gamma = (const float*)d_in[9];
  const float* beta  = (const float*)d_in[10];
  float* out = (float*)d_out;

  char* ws = (char*)d_ws;
  bf16* vbf  = (bf16*)ws;   ws += (size_t)32768 * 1024 * 2;   // 64 MiB, live until k_out
  bf16* Wy   = (bf16*)ws;                                     // 64 MiB
  float* Mp  = (float*)ws;                                    // 16 MiB, aliases Wy slab:
  ws += (size_t)32768 * 1024 * 2;                             // Mp dead before k_wy writes Wy
  bf16* theta = (bf16*)ws;  ws += (size_t)32768 * 256 * 2;    // 16 MiB
  bf16* phiT  = (bf16*)ws;  ws += (size_t)32768 * 256 * 2;    // 16 MiB
  bf16* gT    = (bf16*)ws;  ws += (size_t)32768 * 256 * 2;    // 16 MiB
  bf16* Mbf   = (bf16*)ws;  ws += (size_t)8 * 65536 * 2;      // 1 MiB
  bf16* PT    = (bf16*)ws;  ws += (size_t)8 * 1024 * 256 * 2; // 4 MiB
  bf16* thwb  = (bf16*)ws;  ws += (size_t)256 * 1024 * 2;
  bf16* phwb  = (bf16*)ws;  ws += (size_t)256 * 1024 * 2;
  bf16* gwb   = (bf16*)ws;  ws += (size_t)256 * 1024 * 2;
  bf16* Wwb   = (bf16*)ws;  ws += (size_t)1024 * 256 * 2;
  float* sums = (float*)ws; ws += 4096;
  float* sumsq= (float*)ws; ws += 4096;

  k_cast_all<<<16384 + 512 + 1, 256, 0, stream>>>(v, vbf, th_w, ph_w, g_w, W_w,
                                                  thwb, phwb, gwb, Wwb, sums);

  k_proj <<<dim3(128, 6), 512, 0, stream>>>(vbf, thwb, th_b, phwb, ph_b, gwb, g_b, theta, phiT, gT);
  k_affin<<<dim3(8, 4, 8), 256, 0, stream>>>(phiT, gT, Mp);
  k_mconv<<<512, 256, 0, stream>>>(Mp, Mbf);
  k_pt   <<<dim3(8, 2, 8), 256, 0, stream>>>(Wwb, Mbf, PT);
  k_wy   <<<dim3(128, 8), 512, 0, stream>>>(theta, PT, Wy, sums, sumsq);
  k_out  <<<32768, 256, 0, stream>>>(Wy, vbf, sums, sumsq, gamma, beta, out);
}